// Round 16
// baseline (1632.235 us; speedup 1.0000x reference)
//
#include <hip/hip_runtime.h>
#include <hip/hip_bf16.h>
#include <cstdint>

#define D_DIM 2048
#define F_DIM 1024
#define E_NUM 64
#define K_TOP 8
#define CAP   1024
#define ECHUNK 16

typedef __attribute__((ext_vector_type(8))) short short8;
typedef __attribute__((ext_vector_type(4))) float f32x4;

__device__ __forceinline__ uint16_t f_to_bf16(float f) {
    union { float f; uint32_t u; } v; v.f = f;
    uint32_t r = v.u + 0x7FFF + ((v.u >> 16) & 1);
    return (uint16_t)(r >> 16);
}
__device__ __forceinline__ float bf16_to_f(uint16_t u) {
    union { uint32_t u; float f; } v; v.u = ((uint32_t)u) << 16; return v.f;
}
__device__ __forceinline__ uint32_t pack2(float a, float b) {
    __hip_bfloat162 t = __float22bfloat162_rn(make_float2(a, b));
    return *reinterpret_cast<uint32_t*>(&t);
}
__device__ __forceinline__ void gload16(const void* g, void* l) {
    __builtin_amdgcn_global_load_lds(
        (const __attribute__((address_space(1))) uint32_t*)g,
        (__attribute__((address_space(3))) uint32_t*)l, 16, 0, 0);
}

// ------- weight convert + transpose: src [R][C] f32 -> dst [C][R] bf16 (per e) -------
__global__ __launch_bounds__(256) void cvtw_k(const float* __restrict__ src,
        uint16_t* __restrict__ dst, int R, int C) {
    int e = blockIdx.z;
    int c0 = blockIdx.x * 64;
    int r0 = blockIdx.y * 64;
    __shared__ float ls[64][68];
    int t = threadIdx.x;
    int sr = t >> 2, sc = (t & 3) * 16;
    int skey = ((sr >> 4) & 1) << 4;
    const float* sp = src + (size_t)e * R * C + (size_t)(r0 + sr) * C + c0 + sc;
    #pragma unroll
    for (int j = 0; j < 4; ++j) {
        float4 v = *(const float4*)(sp + j * 4);
        *(float4*)&ls[sr][(sc + j * 4) ^ skey] = v;
    }
    __syncthreads();
    int oc = t >> 2, orr = (t & 3) * 16;
    int rkey = ((orr >> 4) & 1) << 4;
    int occ = oc ^ rkey;
    uint16_t* dp = dst + (size_t)e * C * R + (size_t)(c0 + oc) * R + r0 + orr;
    uint4 o[2];
    uint32_t* ow = (uint32_t*)o;
    #pragma unroll
    for (int j = 0; j < 8; ++j)
        ow[j] = pack2(ls[orr + 2 * j][occ], ls[orr + 2 * j + 1][occ]);
    *(uint4*)(dp) = o[0];
    *(uint4*)(dp + 8) = o[1];
}

// ---------------- Router (+ fused x->bf16 conversion) ----------------
__global__ __launch_bounds__(64) void router_k(const float* __restrict__ x,
        const float* __restrict__ gw, int* __restrict__ topi,
        float* __restrict__ topw, uint16_t* __restrict__ xb) {
    int t = blockIdx.x;
    int tid = threadIdx.x;
    __shared__ float xs[D_DIM];
    __shared__ float lgs[E_NUM];
    const float* xr = x + (size_t)t * D_DIM;
    for (int d = tid; d < D_DIM; d += 64) xs[d] = xr[d];
    __syncthreads();
    uint32_t* xbrow = (uint32_t*)(xb + (size_t)t * D_DIM);
    #pragma unroll
    for (int j = 0; j < D_DIM / 128; ++j) {
        int i = tid + j * 64;
        xbrow[i] = pack2(xs[2 * i], xs[2 * i + 1]);
    }
    const float* w = gw + (size_t)tid * D_DIM;
    float acc = 0.f;
    #pragma unroll 8
    for (int d = 0; d < D_DIM; ++d) acc = fmaf(xs[d], w[d], acc);
    lgs[tid] = acc;
    __syncthreads();
    if (tid == 0) {
        float mx = -INFINITY;
        for (int e = 0; e < E_NUM; ++e) mx = fmaxf(mx, lgs[e]);
        float se = 0.f;
        for (int e = 0; e < E_NUM; ++e) se += expf(lgs[e] - mx);
        float inv = 1.f / se;
        uint64_t used = 0;
        for (int k = 0; k < K_TOP; ++k) {
            int bi = 0; float bv = -INFINITY;
            for (int e = 0; e < E_NUM; ++e) {
                if (!((used >> e) & 1) && lgs[e] > bv) { bv = lgs[e]; bi = e; }
            }
            used |= 1ull << bi;
            topi[t * K_TOP + k] = bi;
            topw[t * K_TOP + k] = expf(bv - mx) * inv;
        }
    }
}

// ---------------- Slot assignment ----------------
__global__ void assign_k(const int* __restrict__ topi, const float* __restrict__ topw,
        int* __restrict__ cnt, int* __restrict__ rowtok, float* __restrict__ aw,
        int* __restrict__ slotof, int T) {
    int t = blockIdx.x * blockDim.x + threadIdx.x;
    if (t >= T) return;
    for (int k = 0; k < K_TOP; ++k) {
        int e = topi[t * K_TOP + k];
        int pos = atomicAdd(&cnt[e], 1);
        if (pos < CAP) {
            rowtok[e * CAP + pos] = t;
            aw[e * CAP + pos] = topw[t * K_TOP + k];
            slotof[t * K_TOP + k] = e * CAP + pos;
        } else {
            slotof[t * K_TOP + k] = -1;
        }
    }
}

// ======== Gate+Up: 128m x 64f, BK=64, gload16 + XOR swizzle (r13 structure),
// chunked over experts so wgt/wut chunk is L3-resident from its cvtw ========
__global__ __launch_bounds__(256) void gateup_k(const uint16_t* __restrict__ xb,
        const uint16_t* __restrict__ wgt, const uint16_t* __restrict__ wut,
        const int* __restrict__ cnt, const int* __restrict__ rowtok,
        uint16_t* __restrict__ h, int e_base) {
    int flat = blockIdx.x;
    int xcd = flat & 7;
    int idx = flat >> 3;
    int m = idx & 7;
    int sloc = idx >> 3;              // 0..31
    int strip = sloc * 8 + xcd;       // 0..255 = (e-e_base)*16 + f
    int e = e_base + (strip >> 4);
    int f = strip & 15;
    int m0 = m * 128;
    int ne = min(cnt[e], CAP);
    int nr = ne - m0;
    if (nr <= 0) return;
    if (nr > 128) nr = 128;
    int slot0 = e * CAP + m0;
    int fbase = f * 64;

    __shared__ __align__(16) uint16_t As[128 * 64];   // 16KB
    __shared__ __align__(16) uint16_t Bg[64 * 64];    // 8KB
    __shared__ __align__(16) uint16_t Bu[64 * 64];    // 8KB

    int tid = threadIdx.x;
    int l = tid & 63, wid = tid >> 6;
    int ln = l & 15, lq = l >> 4;
    int wr = wid >> 1, wc = wid & 1;

    const uint16_t* agp[4];
    #pragma unroll
    for (int i = 0; i < 4; ++i) {
        int c = i * 256 + tid;
        int row = c >> 3, col = c & 7;
        int tok = rowtok[slot0 + min(row, nr - 1)];
        agp[i] = xb + (size_t)tok * D_DIM + ((col ^ (row & 7)) * 8);
    }
    const uint16_t *bgp[2], *bup[2];
    #pragma unroll
    for (int i = 0; i < 2; ++i) {
        int c = i * 256 + tid;
        int row = c >> 3, col = c & 7;
        size_t go = ((size_t)e * F_DIM + fbase + row) * D_DIM + ((col ^ (row & 7)) * 8);
        bgp[i] = wgt + go;
        bup[i] = wut + go;
    }

    f32x4 accg[4][2], accu[4][2];
    #pragma unroll
    for (int mi = 0; mi < 4; ++mi)
        #pragma unroll
        for (int ni = 0; ni < 2; ++ni) {
            accg[mi][ni] = (f32x4){0.f, 0.f, 0.f, 0.f};
            accu[mi][ni] = (f32x4){0.f, 0.f, 0.f, 0.f};
        }

    const int NT = D_DIM / 64;        // 32
    for (int t = 0; t < NT; ++t) {
        int k0 = t * 64;
        #pragma unroll
        for (int i = 0; i < 4; ++i)
            gload16(agp[i] + k0, (char*)As + (i * 256 + wid * 64) * 16);
        #pragma unroll
        for (int i = 0; i < 2; ++i) {
            gload16(bgp[i] + k0, (char*)Bg + (i * 256 + wid * 64) * 16);
            gload16(bup[i] + k0, (char*)Bu + (i * 256 + wid * 64) * 16);
        }
        __syncthreads();
        #pragma unroll
        for (int kk = 0; kk < 2; ++kk) {
            short8 af[4], bg[2], bu[2];
            #pragma unroll
            for (int mi = 0; mi < 4; ++mi) {
                int row = wr * 64 + mi * 16 + ln;
                af[mi] = *(const short8*)((char*)As + row * 128 + (((kk * 4 + lq) ^ (row & 7)) * 16));
            }
            #pragma unroll
            for (int ni = 0; ni < 2; ++ni) {
                int row = wc * 32 + ni * 16 + ln;
                int off = row * 128 + (((kk * 4 + lq) ^ (row & 7)) * 16);
                bg[ni] = *(const short8*)((char*)Bg + off);
                bu[ni] = *(const short8*)((char*)Bu + off);
            }
            #pragma unroll
            for (int mi = 0; mi < 4; ++mi)
                #pragma unroll
                for (int ni = 0; ni < 2; ++ni) {
                    accg[mi][ni] = __builtin_amdgcn_mfma_f32_16x16x32_bf16(af[mi], bg[ni], accg[mi][ni], 0, 0, 0);
                    accu[mi][ni] = __builtin_amdgcn_mfma_f32_16x16x32_bf16(af[mi], bu[ni], accu[mi][ni], 0, 0, 0);
                }
        }
        __syncthreads();
    }

    #pragma unroll
    for (int mi = 0; mi < 4; ++mi) {
        #pragma unroll
        for (int j = 0; j < 4; ++j) {
            int row = wr * 64 + mi * 16 + lq * 4 + j;
            if (row < nr) {
                size_t hb = (size_t)(slot0 + row) * F_DIM + fbase + wc * 32 + ln;
                #pragma unroll
                for (int ni = 0; ni < 2; ++ni) {
                    float g = accg[mi][ni][j], u = accu[mi][ni][j];
                    h[hb + ni * 16] = f_to_bf16(g / (1.f + __expf(-g)) * u);
                }
            }
        }
    }
}

// ======== Down: 128m x 128d, BK=64 (r13 structure), chunked over experts ========
__global__ __launch_bounds__(256) void down_k(const uint16_t* __restrict__ h,
        const uint16_t* __restrict__ wdt, const int* __restrict__ cnt,
        const float* __restrict__ aw, uint16_t* __restrict__ y, int e_base) {
    int flat = blockIdx.x;
    int xcd = flat & 7;
    int idx = flat >> 3;
    int m = idx & 7;
    int sloc = idx >> 3;              // 0..31
    int strip = sloc * 8 + xcd;       // 0..255 = (e-e_base)*16 + dt
    int e = e_base + (strip >> 4);
    int dt = strip & 15;
    int m0 = m * 128;
    int ne = min(cnt[e], CAP);
    int nr = ne - m0;
    if (nr <= 0) return;
    if (nr > 128) nr = 128;
    int slot0 = e * CAP + m0;
    int dbase = dt * 128;

    __shared__ __align__(16) uint16_t As[128 * 64];   // 16KB
    __shared__ __align__(16) uint16_t Bs[128 * 64];   // 16KB

    int tid = threadIdx.x;
    int l = tid & 63, wid = tid >> 6;
    int ln = l & 15, lq = l >> 4;
    int wr = wid >> 1, wc = wid & 1;

    const uint16_t* agp[4];
    #pragma unroll
    for (int i = 0; i < 4; ++i) {
        int c = i * 256 + tid;
        int row = c >> 3, col = c & 7;
        agp[i] = h + (size_t)(slot0 + min(row, nr - 1)) * F_DIM + ((col ^ (row & 7)) * 8);
    }
    const uint16_t* bp[4];
    #pragma unroll
    for (int i = 0; i < 4; ++i) {
        int c = i * 256 + tid;
        int row = c >> 3, col = c & 7;
        bp[i] = wdt + ((size_t)e * D_DIM + dbase + row) * F_DIM + ((col ^ (row & 7)) * 8);
    }

    f32x4 acc[4][4];
    #pragma unroll
    for (int mi = 0; mi < 4; ++mi)
        #pragma unroll
        for (int ni = 0; ni < 4; ++ni)
            acc[mi][ni] = (f32x4){0.f, 0.f, 0.f, 0.f};

    const int NT = F_DIM / 64;        // 16
    for (int t = 0; t < NT; ++t) {
        int k0 = t * 64;
        #pragma unroll
        for (int i = 0; i < 4; ++i)
            gload16(agp[i] + k0, (char*)As + (i * 256 + wid * 64) * 16);
        #pragma unroll
        for (int i = 0; i < 4; ++i)
            gload16(bp[i] + k0, (char*)Bs + (i * 256 + wid * 64) * 16);
        __syncthreads();
        #pragma unroll
        for (int kk = 0; kk < 2; ++kk) {
            short8 af[4], bf[4];
            #pragma unroll
            for (int mi = 0; mi < 4; ++mi) {
                int row = wr * 64 + mi * 16 + ln;
                af[mi] = *(const short8*)((char*)As + row * 128 + (((kk * 4 + lq) ^ (row & 7)) * 16));
            }
            #pragma unroll
            for (int ni = 0; ni < 4; ++ni) {
                int row = wc * 64 + ni * 16 + ln;
                bf[ni] = *(const short8*)((char*)Bs + row * 128 + (((kk * 4 + lq) ^ (row & 7)) * 16));
            }
            #pragma unroll
            for (int mi = 0; mi < 4; ++mi)
                #pragma unroll
                for (int ni = 0; ni < 4; ++ni)
                    acc[mi][ni] = __builtin_amdgcn_mfma_f32_16x16x32_bf16(af[mi], bf[ni], acc[mi][ni], 0, 0, 0);
        }
        __syncthreads();
    }

    #pragma unroll
    for (int mi = 0; mi < 4; ++mi) {
        #pragma unroll
        for (int j = 0; j < 4; ++j) {
            int row = wr * 64 + mi * 16 + lq * 4 + j;
            if (row < nr) {
                int slot = slot0 + row;
                float wgt = aw[slot];
                uint16_t* yrow = y + (size_t)slot * D_DIM + dbase + wc * 64 + ln;
                #pragma unroll
                for (int ni = 0; ni < 4; ++ni)
                    yrow[ni * 16] = f_to_bf16(acc[mi][ni][j] * wgt);
            }
        }
    }
}

// ---------------- Combine: out[t] = sum_k y[slot(t,k)] ----------------
__global__ __launch_bounds__(256) void combine_k(const uint16_t* __restrict__ y,
        const int* __restrict__ slotof, float* __restrict__ out) {
    int t = blockIdx.x;
    int tid = threadIdx.x;
    int sl[K_TOP];
    #pragma unroll
    for (int k = 0; k < K_TOP; ++k) sl[k] = slotof[t * K_TOP + k];
    float acc[8];
    #pragma unroll
    for (int j = 0; j < 8; ++j) acc[j] = 0.f;
    #pragma unroll
    for (int k = 0; k < K_TOP; ++k) {
        if (sl[k] >= 0) {
            const uint16_t* row = y + (size_t)sl[k] * D_DIM;
            #pragma unroll
            for (int j = 0; j < 8; ++j)
                acc[j] += bf16_to_f(row[tid + j * 256]);
        }
    }
    float* orow = out + (size_t)t * D_DIM;
    #pragma unroll
    for (int j = 0; j < 8; ++j)
        orow[tid + j * 256] = acc[j];
}

extern "C" void kernel_launch(void* const* d_in, const int* in_sizes, int n_in,
                              void* d_out, int out_size, void* d_ws, size_t ws_size,
                              hipStream_t stream) {
    const float* x  = (const float*)d_in[0];
    const float* gw = (const float*)d_in[1];
    const float* wg = (const float*)d_in[2];
    const float* wu = (const float*)d_in[3];
    const float* wd = (const float*)d_in[4];
    float* out = (float*)d_out;
    int T = in_sizes[0] / D_DIM;

    char* ws = (char*)d_ws;
    size_t off = 0;
    auto alloc = [&](size_t bytes) -> void* {
        void* p = ws + off;
        off = (off + bytes + 255) & ~(size_t)255;
        return p;
    };
    int*      cnt    = (int*)     alloc(E_NUM * sizeof(int));
    int*      topi   = (int*)     alloc((size_t)T * K_TOP * sizeof(int));
    float*    topw   = (float*)   alloc((size_t)T * K_TOP * sizeof(float));
    int*      rowtok = (int*)     alloc((size_t)E_NUM * CAP * sizeof(int));
    float*    aw     = (float*)   alloc((size_t)E_NUM * CAP * sizeof(float));
    int*      slotof = (int*)     alloc((size_t)T * K_TOP * sizeof(int));
    uint16_t* xb     = (uint16_t*)alloc((size_t)T * D_DIM * sizeof(uint16_t));
    uint16_t* h      = (uint16_t*)alloc((size_t)E_NUM * CAP * F_DIM * sizeof(uint16_t));
    uint16_t* wgt    = (uint16_t*)alloc((size_t)E_NUM * D_DIM * F_DIM * sizeof(uint16_t));
    uint16_t* wut    = (uint16_t*)alloc((size_t)E_NUM * D_DIM * F_DIM * sizeof(uint16_t));
    uint16_t* wdt    = wgt;   // alias: all gateup chunks precede first wd conversion
    uint16_t* y      = wut;   // alias: all gateup chunks precede down writes

    hipMemsetAsync(cnt, 0, E_NUM * sizeof(int), stream);

    router_k<<<T, 64, 0, stream>>>(x, gw, topi, topw, xb);
    assign_k<<<(T + 255) / 256, 256, 0, stream>>>(topi, topw, cnt, rowtok, aw, slotof, T);

    const size_t wsz_gu = (size_t)ECHUNK * D_DIM * F_DIM;   // elements per chunk
    // chunked: convert a 16-expert weight group (134MB bf16, L3-resident),
    // then immediately run its gateup so weight fetches hit L3 not HBM.
    for (int c = 0; c < E_NUM / ECHUNK; ++c) {
        int eb = c * ECHUNK;
        cvtw_k<<<dim3(F_DIM / 64, D_DIM / 64, ECHUNK), 256, 0, stream>>>(
            wg + (size_t)eb * D_DIM * F_DIM, wgt + (size_t)eb * D_DIM * F_DIM, D_DIM, F_DIM);
        cvtw_k<<<dim3(F_DIM / 64, D_DIM / 64, ECHUNK), 256, 0, stream>>>(
            wu + (size_t)eb * D_DIM * F_DIM, wut + (size_t)eb * D_DIM * F_DIM, D_DIM, F_DIM);
        gateup_k<<<ECHUNK * 16 * 8, 256, 0, stream>>>(xb, wgt, wut, cnt, rowtok, h, eb);
    }
    (void)wsz_gu;
    for (int c = 0; c < E_NUM / ECHUNK; ++c) {
        int eb = c * ECHUNK;
        cvtw_k<<<dim3(D_DIM / 64, F_DIM / 64, ECHUNK), 256, 0, stream>>>(
            wd + (size_t)eb * F_DIM * D_DIM, wdt + (size_t)eb * F_DIM * D_DIM, F_DIM, D_DIM);
        down_k<<<ECHUNK * 16 * 8, 256, 0, stream>>>(h, wdt, cnt, aw, y, eb);
    }
    combine_k<<<T, 256, 0, stream>>>(y, slotof, out);
}